// Round 4
// baseline (228.874 us; speedup 1.0000x reference)
//
#include <hip/hip_runtime.h>
#include <hip/hip_bf16.h>

// Problem constants
#define BB 2
#define HH 56
#define WW 56
#define CC 256
#define HEADS 8
#define HD 32
#define KW 7
#define NPIX (BB*HH*WW)           // 6272
#define KV_N 512

using bf16x8 = __attribute__((ext_vector_type(8))) short;
using f32x4  = __attribute__((ext_vector_type(4))) float;

__device__ __forceinline__ ushort f2bf(float f) {
    union { float f; uint u; } v; v.f = f;
    uint r = v.u + 0x7FFF + ((v.u >> 16) & 1);   // round-to-nearest-even
    return (ushort)(r >> 16);
}

// ---------------- bf16 MFMA GEMM: C[M][N] = A[M][K] @ Wt[N][K]^T + bias[N] ----
// (unchanged from round 3)
template<int BM, int BN>
__global__ __launch_bounds__(256) void gemm_bf16_nt(
    const float* __restrict__ A, const float* __restrict__ Wt,
    const float* __restrict__ bias, float* __restrict__ C,
    int M, int N, int Kd)
{
    constexpr int BK  = 64;
    constexpr int LDT = 72;
    constexpr int WTM = BM / 2, WTN = BN / 2;
    constexpr int MF  = WTM / 16, NF = WTN / 16;

    __shared__ ushort As[BM][LDT];
    __shared__ ushort Bs[BN][LDT];

    const int tid  = threadIdx.x;
    const int lane = tid & 63;
    const int wid  = tid >> 6;
    const int wm   = wid >> 1;
    const int wn   = wid & 1;
    const int bm   = blockIdx.y * BM;
    const int bn   = blockIdx.x * BN;

    const int srow = tid >> 3;
    const int skq  = (tid & 7) * 8;

    f32x4 acc[MF][NF] = {};

    for (int k0 = 0; k0 < Kd; k0 += BK) {
        #pragma unroll
        for (int p = 0; p < BM / 32; ++p) {
            const int r = p * 32 + srow;
            const float* src = A + (size_t)(bm + r) * Kd + k0 + skq;
            float4 f0 = *(const float4*)(src);
            float4 f1 = *(const float4*)(src + 4);
            bf16x8 v;
            v[0]=f2bf(f0.x); v[1]=f2bf(f0.y); v[2]=f2bf(f0.z); v[3]=f2bf(f0.w);
            v[4]=f2bf(f1.x); v[5]=f2bf(f1.y); v[6]=f2bf(f1.z); v[7]=f2bf(f1.w);
            *(bf16x8*)&As[r][skq] = v;
        }
        #pragma unroll
        for (int p = 0; p < BN / 32; ++p) {
            const int r = p * 32 + srow;
            const float* src = Wt + (size_t)(bn + r) * Kd + k0 + skq;
            float4 f0 = *(const float4*)(src);
            float4 f1 = *(const float4*)(src + 4);
            bf16x8 v;
            v[0]=f2bf(f0.x); v[1]=f2bf(f0.y); v[2]=f2bf(f0.z); v[3]=f2bf(f0.w);
            v[4]=f2bf(f1.x); v[5]=f2bf(f1.y); v[6]=f2bf(f1.z); v[7]=f2bf(f1.w);
            *(bf16x8*)&Bs[r][skq] = v;
        }
        __syncthreads();

        #pragma unroll
        for (int ks = 0; ks < 2; ++ks) {
            const int koff = ks * 32 + (lane >> 4) * 8;
            bf16x8 af[MF], bf[NF];
            #pragma unroll
            for (int m = 0; m < MF; ++m)
                af[m] = *(const bf16x8*)&As[wm*WTM + m*16 + (lane & 15)][koff];
            #pragma unroll
            for (int n = 0; n < NF; ++n)
                bf[n] = *(const bf16x8*)&Bs[wn*WTN + n*16 + (lane & 15)][koff];
            #pragma unroll
            for (int m = 0; m < MF; ++m)
                #pragma unroll
                for (int n = 0; n < NF; ++n)
                    acc[m][n] = __builtin_amdgcn_mfma_f32_16x16x32_bf16(af[m], bf[n], acc[m][n], 0, 0, 0);
        }
        __syncthreads();
    }

    #pragma unroll
    for (int n = 0; n < NF; ++n) {
        const int col = bn + wn*WTN + n*16 + (lane & 15);
        const float bval = bias[col];
        #pragma unroll
        for (int m = 0; m < MF; ++m) {
            const int row0 = bm + wm*WTM + m*16 + (lane >> 4) * 4;
            #pragma unroll
            for (int r = 0; r < 4; ++r)
                C[(size_t)(row0 + r) * N + col] = acc[m][n][r] + bval;
        }
    }
}

// ---------------- Neighborhood attention, pixel-pair version ----------------
// Thread = (pixel-pair, head, quad-sub of 8 dims). 100352 threads, 392 blocks.
// Pair's two 7-col windows union to <=8 cols -> K/V loaded once for both.
// Scores staged in LDS: sc[64 units][2 pix][52].
__global__ __launch_bounds__(256) void natt_pair(
    const float* __restrict__ q_extra, const float* __restrict__ kv,
    const float* __restrict__ rpb, float* __restrict__ attn_out)
{
    __shared__ float sc[64 * 104];     // 26.6 KB

    const int tid    = threadIdx.x;
    const int gid    = blockIdx.x * 256 + tid;
    const int sub    = gid & 3;
    const int head   = (gid >> 2) & 7;
    const int pairid = gid >> 5;
    const int j0 = (pairid % 28) * 2;
    const int i  = (pairid / 28) % HH;
    const int b  = pairid / (28 * HH);
    float* scu = &sc[(tid >> 2) * 104];

    const int d0 = sub * 8;
    const float scale = 0.17677669529663687f;

    const int pix0 = (b * HH + i) * WW + j0;

    float q[2][8];
    #pragma unroll
    for (int p = 0; p < 2; ++p) {
        const float* qp = q_extra + (size_t)(pix0 + p) * CC + head * HD + d0;
        float4 v0 = *(const float4*)(qp);
        float4 v1 = *(const float4*)(qp + 4);
        q[p][0]=v0.x*scale; q[p][1]=v0.y*scale; q[p][2]=v0.z*scale; q[p][3]=v0.w*scale;
        q[p][4]=v1.x*scale; q[p][5]=v1.y*scale; q[p][6]=v1.z*scale; q[p][7]=v1.w*scale;
    }

    const int sh  = min(max(i - 3, 0), HH - KW);
    const int sw0 = min(max(j0 - 3, 0), WW - KW);
    const int sw1 = min(max(j0 - 2, 0), WW - KW);
    const int o1  = sw1 - sw0;                 // 0 or 1
    const int pbi0  = sh - i + 6;
    const int pbj[2] = { sw0 - j0 + 6, sw1 - (j0 + 1) + 6 };

    // ---- QK pass ----
    for (int a = 0; a < KW; ++a) {
        const float* kbase = kv + ((size_t)((b*HH + sh + a) * WW)) * KV_N + head * HD + d0;
        float kc[8][8];
        #pragma unroll
        for (int cu = 0; cu < 8; ++cu) {
            const int col = min(sw0 + cu, WW - 1);
            const float* kp = kbase + (size_t)col * KV_N;
            float4 v0 = *(const float4*)(kp);
            float4 v1 = *(const float4*)(kp + 4);
            kc[cu][0]=v0.x; kc[cu][1]=v0.y; kc[cu][2]=v0.z; kc[cu][3]=v0.w;
            kc[cu][4]=v1.x; kc[cu][5]=v1.y; kc[cu][6]=v1.z; kc[cu][7]=v1.w;
        }
        const float* bp = rpb + (size_t)head * 169 + (size_t)(pbi0 + a) * 13;
        #pragma unroll
        for (int p = 0; p < 2; ++p) {
            const int op = p ? o1 : 0;
            #pragma unroll
            for (int t = 0; t < KW; ++t) {
                float v = q[p][0]*kc[op+t][0] + q[p][1]*kc[op+t][1]
                        + q[p][2]*kc[op+t][2] + q[p][3]*kc[op+t][3]
                        + q[p][4]*kc[op+t][4] + q[p][5]*kc[op+t][5]
                        + q[p][6]*kc[op+t][6] + q[p][7]*kc[op+t][7];
                v += __shfl_xor(v, 1);
                v += __shfl_xor(v, 2);
                v += bp[pbj[p] + t];
                if ((t & 3) == sub) scu[p*52 + a*KW + t] = v;   // distributed write
            }
        }
    }
    __syncthreads();

    // ---- softmax (each sub owns a 13-slice of the 49 scores) ----
    #pragma unroll
    for (int p = 0; p < 2; ++p) {
        const int base = p*52 + sub*13;
        const int n = (sub == 3) ? 10 : 13;
        float r[13];
        float m = -3.4e38f;
        #pragma unroll
        for (int k = 0; k < 13; ++k) {
            r[k] = (k < n) ? scu[base + k] : -3.4e38f;
            m = fmaxf(m, r[k]);
        }
        m = fmaxf(m, __shfl_xor(m, 1));
        m = fmaxf(m, __shfl_xor(m, 2));
        float l = 0.f;
        #pragma unroll
        for (int k = 0; k < 13; ++k) {
            r[k] = __expf(r[k] - m);
            l += r[k];
        }
        l += __shfl_xor(l, 1);
        l += __shfl_xor(l, 2);
        const float inv = 1.0f / l;
        #pragma unroll
        for (int k = 0; k < 13; ++k)
            if (k < n) scu[base + k] = r[k] * inv;
    }
    __syncthreads();

    // ---- PV pass ----
    float acc[2][8] = {};
    for (int a = 0; a < KW; ++a) {
        const float* vbase = kv + ((size_t)((b*HH + sh + a) * WW)) * KV_N + CC + head * HD + d0;
        float vc[8][8];
        #pragma unroll
        for (int cu = 0; cu < 8; ++cu) {
            const int col = min(sw0 + cu, WW - 1);
            const float* vp = vbase + (size_t)col * KV_N;
            float4 v0 = *(const float4*)(vp);
            float4 v1 = *(const float4*)(vp + 4);
            vc[cu][0]=v0.x; vc[cu][1]=v0.y; vc[cu][2]=v0.z; vc[cu][3]=v0.w;
            vc[cu][4]=v1.x; vc[cu][5]=v1.y; vc[cu][6]=v1.z; vc[cu][7]=v1.w;
        }
        #pragma unroll
        for (int p = 0; p < 2; ++p) {
            const int op = p ? o1 : 0;
            #pragma unroll
            for (int t = 0; t < KW; ++t) {
                const float pv = scu[p*52 + a*KW + t];
                #pragma unroll
                for (int d = 0; d < 8; ++d)
                    acc[p][d] += pv * vc[op+t][d];
            }
        }
    }

    #pragma unroll
    for (int p = 0; p < 2; ++p) {
        float* op_ = attn_out + (size_t)(pix0 + p) * CC + head * HD + d0;
        float4 o0, o1v;
        o0.x=acc[p][0]; o0.y=acc[p][1]; o0.z=acc[p][2]; o0.w=acc[p][3];
        o1v.x=acc[p][4]; o1v.y=acc[p][5]; o1v.z=acc[p][6]; o1v.w=acc[p][7];
        *(float4*)(op_)     = o0;
        *(float4*)(op_ + 4) = o1v;
    }
}

extern "C" void kernel_launch(void* const* d_in, const int* in_sizes, int n_in,
                              void* d_out, int out_size, void* d_ws, size_t ws_size,
                              hipStream_t stream) {
    const float* x       = (const float*)d_in[0];
    const float* q_extra = (const float*)d_in[1];
    const float* kv_w    = (const float*)d_in[2];
    const float* kv_b    = (const float*)d_in[3];
    const float* rpb     = (const float*)d_in[4];
    const float* proj_w  = (const float*)d_in[5];
    const float* proj_b  = (const float*)d_in[6];
    float* out = (float*)d_out;

    float* kv       = (float*)d_ws;                      // NPIX * 512 floats
    float* attn_out = kv + (size_t)NPIX * KV_N;          // NPIX * 256 floats

    // 1) kv = x @ kv_w^T + kv_b   (M=6272, N=512, K=256), MFMA bf16
    {
        dim3 grid(KV_N/64, NPIX/128);
        gemm_bf16_nt<128,64><<<grid, 256, 0, stream>>>(x, kv_w, kv_b, kv, NPIX, KV_N, CC);
    }
    // 2) neighborhood attention (pixel-pair, 392 blocks)
    {
        dim3 grid((NPIX/2 * HEADS * 4) / 256);
        natt_pair<<<grid, 256, 0, stream>>>(q_extra, kv, rpb, attn_out);
    }
    // 3) out = attn_out @ proj_w^T + proj_b   (M=6272, N=256, K=256), MFMA bf16
    {
        dim3 grid(CC/64, NPIX/64);
        gemm_bf16_nt<64,64><<<grid, 256, 0, stream>>>(attn_out, proj_w, proj_b, out, NPIX, CC, CC);
    }
}

// Round 5
// 116.405 us; speedup vs baseline: 1.9662x; 1.9662x over previous
//
#include <hip/hip_runtime.h>
#include <hip/hip_bf16.h>

// Problem constants
#define BB 2
#define HH 56
#define WW 56
#define CC 256
#define HEADS 8
#define HD 32
#define KW 7
#define NPIX (BB*HH*WW)           // 6272
#define KV_N 512

using bf16x8 = __attribute__((ext_vector_type(8))) short;
using f32x4  = __attribute__((ext_vector_type(4))) float;

__device__ __forceinline__ ushort f2bf(float f) {
    union { float f; uint u; } v; v.f = f;
    uint r = v.u + 0x7FFF + ((v.u >> 16) & 1);   // round-to-nearest-even
    return (ushort)(r >> 16);
}

// ---------------- bf16 MFMA GEMM: C[M][N] = A[M][K] @ Wt[N][K]^T + bias[N] ----
// (unchanged from round 3)
template<int BM, int BN>
__global__ __launch_bounds__(256) void gemm_bf16_nt(
    const float* __restrict__ A, const float* __restrict__ Wt,
    const float* __restrict__ bias, float* __restrict__ C,
    int M, int N, int Kd)
{
    constexpr int BK  = 64;
    constexpr int LDT = 72;
    constexpr int WTM = BM / 2, WTN = BN / 2;
    constexpr int MF  = WTM / 16, NF = WTN / 16;

    __shared__ ushort As[BM][LDT];
    __shared__ ushort Bs[BN][LDT];

    const int tid  = threadIdx.x;
    const int lane = tid & 63;
    const int wid  = tid >> 6;
    const int wm   = wid >> 1;
    const int wn   = wid & 1;
    const int bm   = blockIdx.y * BM;
    const int bn   = blockIdx.x * BN;

    const int srow = tid >> 3;
    const int skq  = (tid & 7) * 8;

    f32x4 acc[MF][NF] = {};

    for (int k0 = 0; k0 < Kd; k0 += BK) {
        #pragma unroll
        for (int p = 0; p < BM / 32; ++p) {
            const int r = p * 32 + srow;
            const float* src = A + (size_t)(bm + r) * Kd + k0 + skq;
            float4 f0 = *(const float4*)(src);
            float4 f1 = *(const float4*)(src + 4);
            bf16x8 v;
            v[0]=f2bf(f0.x); v[1]=f2bf(f0.y); v[2]=f2bf(f0.z); v[3]=f2bf(f0.w);
            v[4]=f2bf(f1.x); v[5]=f2bf(f1.y); v[6]=f2bf(f1.z); v[7]=f2bf(f1.w);
            *(bf16x8*)&As[r][skq] = v;
        }
        #pragma unroll
        for (int p = 0; p < BN / 32; ++p) {
            const int r = p * 32 + srow;
            const float* src = Wt + (size_t)(bn + r) * Kd + k0 + skq;
            float4 f0 = *(const float4*)(src);
            float4 f1 = *(const float4*)(src + 4);
            bf16x8 v;
            v[0]=f2bf(f0.x); v[1]=f2bf(f0.y); v[2]=f2bf(f0.z); v[3]=f2bf(f0.w);
            v[4]=f2bf(f1.x); v[5]=f2bf(f1.y); v[6]=f2bf(f1.z); v[7]=f2bf(f1.w);
            *(bf16x8*)&Bs[r][skq] = v;
        }
        __syncthreads();

        #pragma unroll
        for (int ks = 0; ks < 2; ++ks) {
            const int koff = ks * 32 + (lane >> 4) * 8;
            bf16x8 af[MF], bf[NF];
            #pragma unroll
            for (int m = 0; m < MF; ++m)
                af[m] = *(const bf16x8*)&As[wm*WTM + m*16 + (lane & 15)][koff];
            #pragma unroll
            for (int n = 0; n < NF; ++n)
                bf[n] = *(const bf16x8*)&Bs[wn*WTN + n*16 + (lane & 15)][koff];
            #pragma unroll
            for (int m = 0; m < MF; ++m)
                #pragma unroll
                for (int n = 0; n < NF; ++n)
                    acc[m][n] = __builtin_amdgcn_mfma_f32_16x16x32_bf16(af[m], bf[n], acc[m][n], 0, 0, 0);
        }
        __syncthreads();
    }

    #pragma unroll
    for (int n = 0; n < NF; ++n) {
        const int col = bn + wn*WTN + n*16 + (lane & 15);
        const float bval = bias[col];
        #pragma unroll
        for (int m = 0; m < MF; ++m) {
            const int row0 = bm + wm*WTM + m*16 + (lane >> 4) * 4;
            #pragma unroll
            for (int r = 0; r < 4; ++r)
                C[(size_t)(row0 + r) * N + col] = acc[m][n][r] + bval;
        }
    }
}

// ---------------- Neighborhood attention, LDS-tiled ----------------
// Block = (batch, 8x8 pixel tile, head). Stage the 14x14-pixel K/V window
// for this head into LDS once; thread = (pixel, 8-dim sub).
// LDS stride 36 floats (144B) breaks the 128B bank alias.
// All register arrays are compile-time indexed (rule #20).
__global__ __launch_bounds__(256) void natt_tile(
    const float* __restrict__ q_extra, const float* __restrict__ kv,
    const float* __restrict__ rpb, float* __restrict__ attn_out)
{
    __shared__ float Ks[196 * 36];     // 28.2 KB
    __shared__ float Vs[196 * 36];     // 28.2 KB

    const int blk  = blockIdx.x;
    const int head = blk & 7;
    const int t    = blk >> 3;          // 0..97
    const int tj   = t % 7;
    const int ti   = (t / 7) % 7;
    const int b    = t / 49;

    const int r0 = max(0, ti * 8 - 3);
    const int c0 = max(0, tj * 8 - 3);

    const int tid = threadIdx.x;

    // ---- stage K/V (14x14 pixels, source coords clamped; dupes never read) ----
    for (int e = tid; e < 196 * 8; e += 256) {
        const int spix = e >> 3;
        const int f4   = e & 7;
        const int wr   = spix / 14;
        const int wc   = spix - wr * 14;
        const int gr   = min(r0 + wr, HH - 1);
        const int gc   = min(c0 + wc, WW - 1);
        const float* src = kv + ((size_t)((b * HH + gr) * WW + gc)) * KV_N + head * HD + f4 * 4;
        float4 kq = *(const float4*)(src);
        float4 vq = *(const float4*)(src + CC);
        *(float4*)&Ks[spix * 36 + f4 * 4] = kq;
        *(float4*)&Vs[spix * 36 + f4 * 4] = vq;
    }

    const int sub = tid & 3;
    const int p   = tid >> 2;           // 0..63
    const int li  = p >> 3, lj = p & 7;
    const int i = ti * 8 + li, j = tj * 8 + lj;
    const int pix = (b * HH + i) * WW + j;
    const int d0 = sub * 8;

    const float scale = 0.17677669529663687f;  // 32^-0.5
    float q[8];
    {
        const float* qp = q_extra + (size_t)pix * CC + head * HD + d0;
        float4 v0 = *(const float4*)(qp);
        float4 v1 = *(const float4*)(qp + 4);
        q[0]=v0.x*scale; q[1]=v0.y*scale; q[2]=v0.z*scale; q[3]=v0.w*scale;
        q[4]=v1.x*scale; q[5]=v1.y*scale; q[6]=v1.z*scale; q[7]=v1.w*scale;
    }

    const int sh = min(max(i - 3, 0), HH - KW);
    const int sw = min(max(j - 3, 0), WW - KW);
    const int wr0 = sh - r0;            // 0..7
    const int wc0 = sw - c0;            // 0..7
    const int pbi0 = sh - i + 6;
    const int pbj0 = sw - j + 6;

    __syncthreads();

    // ---- QK + bias, quad-reduced; scores fully in registers ----
    float s[49];
    float mmax = -3.4e38f;
    #pragma unroll
    for (int a = 0; a < KW; ++a) {
        const float* kr = &Ks[((wr0 + a) * 14 + wc0) * 36 + d0];
        const float* bp = rpb + (size_t)head * 169 + (size_t)(pbi0 + a) * 13 + pbj0;
        #pragma unroll
        for (int c = 0; c < KW; ++c) {
            float4 k0 = *(const float4*)(kr + c * 36);
            float4 k1 = *(const float4*)(kr + c * 36 + 4);
            float v = q[0]*k0.x + q[1]*k0.y + q[2]*k0.z + q[3]*k0.w
                    + q[4]*k1.x + q[5]*k1.y + q[6]*k1.z + q[7]*k1.w;
            v += __shfl_xor(v, 1);
            v += __shfl_xor(v, 2);
            v += bp[c];
            s[a * KW + c] = v;
            mmax = fmaxf(mmax, v);
        }
    }

    float sum = 0.f;
    #pragma unroll
    for (int k = 0; k < KW * KW; ++k) {
        s[k] = __expf(s[k] - mmax);
        sum += s[k];
    }
    const float inv = 1.0f / sum;

    // ---- PV from LDS ----
    float acc[8] = {};
    #pragma unroll
    for (int a = 0; a < KW; ++a) {
        const float* vr = &Vs[((wr0 + a) * 14 + wc0) * 36 + d0];
        #pragma unroll
        for (int c = 0; c < KW; ++c) {
            float4 v0 = *(const float4*)(vr + c * 36);
            float4 v1 = *(const float4*)(vr + c * 36 + 4);
            const float w = s[a * KW + c];
            acc[0] += w*v0.x; acc[1] += w*v0.y; acc[2] += w*v0.z; acc[3] += w*v0.w;
            acc[4] += w*v1.x; acc[5] += w*v1.y; acc[6] += w*v1.z; acc[7] += w*v1.w;
        }
    }

    float* op = attn_out + (size_t)pix * CC + head * HD + d0;
    float4 o0, o1;
    o0.x = acc[0]*inv; o0.y = acc[1]*inv; o0.z = acc[2]*inv; o0.w = acc[3]*inv;
    o1.x = acc[4]*inv; o1.y = acc[5]*inv; o1.z = acc[6]*inv; o1.w = acc[7]*inv;
    *(float4*)(op)     = o0;
    *(float4*)(op + 4) = o1;
}

extern "C" void kernel_launch(void* const* d_in, const int* in_sizes, int n_in,
                              void* d_out, int out_size, void* d_ws, size_t ws_size,
                              hipStream_t stream) {
    const float* x       = (const float*)d_in[0];
    const float* q_extra = (const float*)d_in[1];
    const float* kv_w    = (const float*)d_in[2];
    const float* kv_b    = (const float*)d_in[3];
    const float* rpb     = (const float*)d_in[4];
    const float* proj_w  = (const float*)d_in[5];
    const float* proj_b  = (const float*)d_in[6];
    float* out = (float*)d_out;

    float* kv       = (float*)d_ws;                      // NPIX * 512 floats
    float* attn_out = kv + (size_t)NPIX * KV_N;          // NPIX * 256 floats

    // 1) kv = x @ kv_w^T + kv_b   (M=6272, N=512, K=256), MFMA bf16
    {
        dim3 grid(KV_N/64, NPIX/128);
        gemm_bf16_nt<128,64><<<grid, 256, 0, stream>>>(x, kv_w, kv_b, kv, NPIX, KV_N, CC);
    }
    // 2) neighborhood attention (LDS-tiled: 2 batches x 49 tiles x 8 heads)
    {
        dim3 grid(BB * 49 * HEADS);
        natt_tile<<<grid, 256, 0, stream>>>(q_extra, kv, rpb, attn_out);
    }
    // 3) out = attn_out @ proj_w^T + proj_b   (M=6272, N=256, K=256), MFMA bf16
    {
        dim3 grid(CC/64, NPIX/64);
        gemm_bf16_nt<64,64><<<grid, 256, 0, stream>>>(attn_out, proj_w, proj_b, out, NPIX, CC, CC);
    }
}

// Round 6
// 115.209 us; speedup vs baseline: 1.9866x; 1.0104x over previous
//
#include <hip/hip_runtime.h>
#include <hip/hip_bf16.h>

// Problem constants
#define BB 2
#define HH 56
#define WW 56
#define CC 256
#define HEADS 8
#define HD 32
#define KW 7
#define NPIX (BB*HH*WW)           // 6272
#define KV_N 512

using bf16x8 = __attribute__((ext_vector_type(8))) short;
using f32x4  = __attribute__((ext_vector_type(4))) float;

__device__ __forceinline__ ushort f2bf(float f) {
    union { float f; uint u; } v; v.f = f;
    uint r = v.u + 0x7FFF + ((v.u >> 16) & 1);   // round-to-nearest-even
    return (ushort)(r >> 16);
}
__device__ __forceinline__ float bf2f(ushort h) {
    union { uint u; float f; } v; v.u = ((uint)h) << 16;
    return v.f;
}

// ---- bf16 MFMA GEMM: C[M][N] = A[M][K] @ Wt[N][K]^T + bias[N] ----
// A_BF16: A is already bf16 (direct-copy staging). OUT_BF16: store C as bf16.
template<int BM, int BN, bool A_BF16, bool OUT_BF16>
__global__ __launch_bounds__(256) void gemm_bf16_nt(
    const void* __restrict__ Av, const float* __restrict__ Wt,
    const float* __restrict__ bias, void* __restrict__ Cv,
    int M, int N, int Kd)
{
    constexpr int BK  = 64;
    constexpr int LDT = 72;
    constexpr int WTM = BM / 2, WTN = BN / 2;
    constexpr int MF  = WTM / 16, NF = WTN / 16;

    __shared__ ushort As[BM][LDT];
    __shared__ ushort Bs[BN][LDT];

    const int tid  = threadIdx.x;
    const int lane = tid & 63;
    const int wid  = tid >> 6;
    const int wm   = wid >> 1;
    const int wn   = wid & 1;
    const int bm   = blockIdx.y * BM;
    const int bn   = blockIdx.x * BN;

    const int srow = tid >> 3;
    const int skq  = (tid & 7) * 8;

    f32x4 acc[MF][NF] = {};

    for (int k0 = 0; k0 < Kd; k0 += BK) {
        #pragma unroll
        for (int p = 0; p < BM / 32; ++p) {
            const int r = p * 32 + srow;
            if constexpr (A_BF16) {
                const ushort* src = (const ushort*)Av + (size_t)(bm + r) * Kd + k0 + skq;
                *(bf16x8*)&As[r][skq] = *(const bf16x8*)src;
            } else {
                const float* src = (const float*)Av + (size_t)(bm + r) * Kd + k0 + skq;
                float4 f0 = *(const float4*)(src);
                float4 f1 = *(const float4*)(src + 4);
                bf16x8 v;
                v[0]=f2bf(f0.x); v[1]=f2bf(f0.y); v[2]=f2bf(f0.z); v[3]=f2bf(f0.w);
                v[4]=f2bf(f1.x); v[5]=f2bf(f1.y); v[6]=f2bf(f1.z); v[7]=f2bf(f1.w);
                *(bf16x8*)&As[r][skq] = v;
            }
        }
        #pragma unroll
        for (int p = 0; p < BN / 32; ++p) {
            const int r = p * 32 + srow;
            const float* src = Wt + (size_t)(bn + r) * Kd + k0 + skq;
            float4 f0 = *(const float4*)(src);
            float4 f1 = *(const float4*)(src + 4);
            bf16x8 v;
            v[0]=f2bf(f0.x); v[1]=f2bf(f0.y); v[2]=f2bf(f0.z); v[3]=f2bf(f0.w);
            v[4]=f2bf(f1.x); v[5]=f2bf(f1.y); v[6]=f2bf(f1.z); v[7]=f2bf(f1.w);
            *(bf16x8*)&Bs[r][skq] = v;
        }
        __syncthreads();

        #pragma unroll
        for (int ks = 0; ks < 2; ++ks) {
            const int koff = ks * 32 + (lane >> 4) * 8;
            bf16x8 af[MF], bf[NF];
            #pragma unroll
            for (int m = 0; m < MF; ++m)
                af[m] = *(const bf16x8*)&As[wm*WTM + m*16 + (lane & 15)][koff];
            #pragma unroll
            for (int n = 0; n < NF; ++n)
                bf[n] = *(const bf16x8*)&Bs[wn*WTN + n*16 + (lane & 15)][koff];
            #pragma unroll
            for (int m = 0; m < MF; ++m)
                #pragma unroll
                for (int n = 0; n < NF; ++n)
                    acc[m][n] = __builtin_amdgcn_mfma_f32_16x16x32_bf16(af[m], bf[n], acc[m][n], 0, 0, 0);
        }
        __syncthreads();
    }

    #pragma unroll
    for (int n = 0; n < NF; ++n) {
        const int col = bn + wn*WTN + n*16 + (lane & 15);
        const float bval = bias[col];
        #pragma unroll
        for (int m = 0; m < MF; ++m) {
            const int row0 = bm + wm*WTM + m*16 + (lane >> 4) * 4;
            #pragma unroll
            for (int r = 0; r < 4; ++r) {
                const float o = acc[m][n][r] + bval;
                if constexpr (OUT_BF16)
                    ((ushort*)Cv)[(size_t)(row0 + r) * N + col] = f2bf(o);
                else
                    ((float*)Cv)[(size_t)(row0 + r) * N + col] = o;
            }
        }
    }
}

// ---- Neighborhood attention, LDS-tiled; kv input bf16, attn_out bf16 ----
// Block = (batch, 8x8 pixel tile, head). Stage 14x14 K/V window (bf16 -> f32)
// into LDS once; thread = (pixel, 8-dim sub). Inner loops all-f32, identical
// to the verified round-5 structure; all register arrays compile-time indexed.
__global__ __launch_bounds__(256) void natt_tile(
    const float* __restrict__ q_extra, const ushort* __restrict__ kv,
    const float* __restrict__ rpb, ushort* __restrict__ attn_out)
{
    __shared__ float Ks[196 * 36];     // 28.2 KB
    __shared__ float Vs[196 * 36];     // 28.2 KB

    const int blk  = blockIdx.x;
    const int head = blk & 7;
    const int t    = blk >> 3;          // 0..97
    const int tj   = t % 7;
    const int ti   = (t / 7) % 7;
    const int b    = t / 49;

    const int r0 = max(0, ti * 8 - 3);
    const int c0 = max(0, tj * 8 - 3);

    const int tid = threadIdx.x;

    // stage: e -> (pixel, half(K/V), 8-dim chunk); bf16x8 load, f32 LDS write
    for (int e = tid; e < 196 * 8; e += 256) {
        const int spix  = e >> 3;
        const int f4    = e & 7;
        const int half  = f4 >> 2;           // 0 = K, 1 = V
        const int chunk = f4 & 3;            // 8-dim chunk
        const int wr   = spix / 14;
        const int wc   = spix - wr * 14;
        const int gr   = min(r0 + wr, HH - 1);
        const int gc   = min(c0 + wc, WW - 1);
        const ushort* src = kv + ((size_t)((b * HH + gr) * WW + gc)) * KV_N
                               + half * CC + head * HD + chunk * 8;
        bf16x8 v = *(const bf16x8*)src;
        float* dst = (half ? Vs : Ks) + spix * 36 + chunk * 8;
        float4 lo, hi;
        lo.x = bf2f((ushort)v[0]); lo.y = bf2f((ushort)v[1]);
        lo.z = bf2f((ushort)v[2]); lo.w = bf2f((ushort)v[3]);
        hi.x = bf2f((ushort)v[4]); hi.y = bf2f((ushort)v[5]);
        hi.z = bf2f((ushort)v[6]); hi.w = bf2f((ushort)v[7]);
        *(float4*)(dst)     = lo;
        *(float4*)(dst + 4) = hi;
    }

    const int sub = tid & 3;
    const int p   = tid >> 2;           // 0..63
    const int li  = p >> 3, lj = p & 7;
    const int i = ti * 8 + li, j = tj * 8 + lj;
    const int pix = (b * HH + i) * WW + j;
    const int d0 = sub * 8;

    const float scale = 0.17677669529663687f;  // 32^-0.5
    float q[8];
    {
        const float* qp = q_extra + (size_t)pix * CC + head * HD + d0;
        float4 v0 = *(const float4*)(qp);
        float4 v1 = *(const float4*)(qp + 4);
        q[0]=v0.x*scale; q[1]=v0.y*scale; q[2]=v0.z*scale; q[3]=v0.w*scale;
        q[4]=v1.x*scale; q[5]=v1.y*scale; q[6]=v1.z*scale; q[7]=v1.w*scale;
    }

    const int sh = min(max(i - 3, 0), HH - KW);
    const int sw = min(max(j - 3, 0), WW - KW);
    const int wr0 = sh - r0;            // 0..7
    const int wc0 = sw - c0;            // 0..7
    const int pbi0 = sh - i + 6;
    const int pbj0 = sw - j + 6;

    __syncthreads();

    // QK + bias, quad-reduced; scores in registers
    float s[49];
    float mmax = -3.4e38f;
    #pragma unroll
    for (int a = 0; a < KW; ++a) {
        const float* kr = &Ks[((wr0 + a) * 14 + wc0) * 36 + d0];
        const float* bp = rpb + (size_t)head * 169 + (size_t)(pbi0 + a) * 13 + pbj0;
        #pragma unroll
        for (int c = 0; c < KW; ++c) {
            float4 k0 = *(const float4*)(kr + c * 36);
            float4 k1 = *(const float4*)(kr + c * 36 + 4);
            float v = q[0]*k0.x + q[1]*k0.y + q[2]*k0.z + q[3]*k0.w
                    + q[4]*k1.x + q[5]*k1.y + q[6]*k1.z + q[7]*k1.w;
            v += __shfl_xor(v, 1);
            v += __shfl_xor(v, 2);
            v += bp[c];
            s[a * KW + c] = v;
            mmax = fmaxf(mmax, v);
        }
    }

    float sum = 0.f;
    #pragma unroll
    for (int k = 0; k < KW * KW; ++k) {
        s[k] = __expf(s[k] - mmax);
        sum += s[k];
    }
    const float inv = 1.0f / sum;

    // PV from LDS
    float acc[8] = {};
    #pragma unroll
    for (int a = 0; a < KW; ++a) {
        const float* vr = &Vs[((wr0 + a) * 14 + wc0) * 36 + d0];
        #pragma unroll
        for (int c = 0; c < KW; ++c) {
            float4 v0 = *(const float4*)(vr + c * 36);
            float4 v1 = *(const float4*)(vr + c * 36 + 4);
            const float w = s[a * KW + c];
            acc[0] += w*v0.x; acc[1] += w*v0.y; acc[2] += w*v0.z; acc[3] += w*v0.w;
            acc[4] += w*v1.x; acc[5] += w*v1.y; acc[6] += w*v1.z; acc[7] += w*v1.w;
        }
    }

    ushort* op = attn_out + (size_t)pix * CC + head * HD + d0;
    bf16x8 o;
    o[0]=f2bf(acc[0]*inv); o[1]=f2bf(acc[1]*inv);
    o[2]=f2bf(acc[2]*inv); o[3]=f2bf(acc[3]*inv);
    o[4]=f2bf(acc[4]*inv); o[5]=f2bf(acc[5]*inv);
    o[6]=f2bf(acc[6]*inv); o[7]=f2bf(acc[7]*inv);
    *(bf16x8*)op = o;
}

extern "C" void kernel_launch(void* const* d_in, const int* in_sizes, int n_in,
                              void* d_out, int out_size, void* d_ws, size_t ws_size,
                              hipStream_t stream) {
    const float* x       = (const float*)d_in[0];
    const float* q_extra = (const float*)d_in[1];
    const float* kv_w    = (const float*)d_in[2];
    const float* kv_b    = (const float*)d_in[3];
    const float* rpb     = (const float*)d_in[4];
    const float* proj_w  = (const float*)d_in[5];
    const float* proj_b  = (const float*)d_in[6];
    float* out = (float*)d_out;

    ushort* kv       = (ushort*)d_ws;                      // NPIX*512 bf16 = 6.4 MB
    ushort* attn_out = kv + (size_t)NPIX * KV_N;           // NPIX*256 bf16 = 3.2 MB

    // 1) kv = bf16( x @ kv_w^T + kv_b )   (M=6272, N=512, K=256)
    {
        dim3 grid(KV_N/64, NPIX/128);
        gemm_bf16_nt<128,64,false,true><<<grid, 256, 0, stream>>>(x, kv_w, kv_b, kv, NPIX, KV_N, CC);
    }
    // 2) neighborhood attention (bf16 in/out, f32 compute in LDS/regs)
    {
        dim3 grid(BB * 49 * HEADS);
        natt_tile<<<grid, 256, 0, stream>>>(q_extra, kv, rpb, attn_out);
    }
    // 3) out = attn_out(bf16) @ proj_w^T + proj_b   (M=6272, N=256, K=256)
    {
        dim3 grid(CC/64, NPIX/64);
        gemm_bf16_nt<64,64,true,false><<<grid, 256, 0, stream>>>(attn_out, proj_w, proj_b, out, NPIX, CC, CC);
    }
}